// Round 7
// baseline (225.031 us; speedup 1.0000x reference)
//
#include <hip/hip_runtime.h>
#include <math.h>

typedef unsigned short u16;
typedef __attribute__((ext_vector_type(4))) float f32x4;
typedef __attribute__((ext_vector_type(8))) short bf16x8;

#define SEQ   2048
#define EMB   1024
#define NH    16
#define HD    64
#define MROWS 4096   // B*S

__device__ __forceinline__ u16 f2b(float f) {
    unsigned u = __float_as_uint(f);
    u += 0x7fff + ((u >> 16) & 1);   // RNE
    return (u16)(u >> 16);
}
__device__ __forceinline__ unsigned pack_bf16x2(float a, float b) {
    unsigned ua = __float_as_uint(a) + 0x8000u;
    unsigned ub = __float_as_uint(b) + 0x8000u;
    return __builtin_amdgcn_perm(ub, ua, 0x07060302u);
}
__device__ __forceinline__ void gld16(const u16* g, const u16* l) {
    __builtin_amdgcn_global_load_lds((const __attribute__((address_space(1))) void*)g,
                                     (__attribute__((address_space(3))) void*)l, 16, 0, 0);
}

// ---------------- fp32 -> bf16 convert + RoPE table (single merged dispatch) ----------------
struct F2BArgs { const float* s[7]; u16* d[7]; float2* tbl; };

__global__ void k_f2b(F2BArgs a) {
    int id = blockIdx.x;
    if (id >= 8192) {             // RoPE cos/sin table: [S=2048][32] float2
        int base = ((id - 8192) * 256 + threadIdx.x) * 4;
#pragma unroll
        for (int e = 0; e < 4; e++) {
            int idx = base + e;
            int s = idx >> 5, d = idx & 31;
            float inv = __expf(-(float)d * 0.28782313662425575f);  // ln(10000)/32
            float ang = (float)s * inv;
            a.tbl[idx] = make_float2(cosf(ang), sinf(ang));
        }
        return;
    }
    const float* src; u16* dst; int base;
    if (id < 6144) {              // 3 activation tensors, 2048 blocks each
        int z = id >> 11;
        src = a.s[z]; dst = a.d[z];
        base = (id & 2047) << 8;
    } else {                      // 4 weight tensors, 512 blocks each
        int r = id - 6144;
        int z = 3 + (r >> 9);
        src = a.s[z]; dst = a.d[z];
        base = (r & 511) << 8;
    }
    int i = base + threadIdx.x;   // index in units of 8 elements
    const float4* s4 = (const float4*)src;
    float4 x = s4[i * 2], y = s4[i * 2 + 1];
    union { u16 u[8]; uint4 v; } o;
    o.u[0] = f2b(x.x); o.u[1] = f2b(x.y); o.u[2] = f2b(x.z); o.u[3] = f2b(x.w);
    o.u[4] = f2b(y.x); o.u[5] = f2b(y.y); o.u[6] = f2b(y.z); o.u[7] = f2b(y.w);
    ((uint4*)dst)[i] = o.v;
}

// ---------------- QKV GEMM: C[M,N] = A[M,K] @ B[N,K]^T + bias ----------------
// PROVEN round-3/5 structure (42 us): BM=256 x BN=128, BK=64, 8 waves, 3
// K-tile LDS buffers (144 KB), conflict-free p^(row&7) swizzle, counted
// vmcnt, 2-phase per tile. 256x256 (R6) and 128x128 (R4) both regressed;
// this is the plateau of the 2-barrier structure (~600 TF).
// Epilogue: RoPE via precomputed table (replaces 64x __sincosf/thread).
struct GemmArgs {
    const u16* A; const u16* Bw; const float* bias; u16* Cb; const float2* rope;
};

__global__ __launch_bounds__(512, 2) void k_gemm_qkv(GemmArgs g0, GemmArgs g1, GemmArgs g2) {
    __shared__ u16 sbuf[3][24576];   // 3 K-tile buffers: A 256x64 (16K u16) + B 128x64 (8K u16)

    int id = blockIdx.x;
    int x = id / 48;
    int rem = id % 48;
    int z = rem >> 4;
    int y = rem & 15;
    GemmArgs g = (z == 0) ? g0 : (z == 1 ? g1 : g2);

    int tid = threadIdx.x;
    int wave = tid >> 6, lane = tid & 63, quad = lane >> 4, l16 = lane & 15;
    int wm = wave >> 1, wn = wave & 1;
    int m0 = y * 256, n0 = x * 128;
    const int K = EMB;

    // half h: pp in [h*3, h*3+3) of the 6 512-thread load chunks (3 loads/thread)
    auto stage_half = [&](int k0, u16* buf, int h) {
#pragma unroll
        for (int pp = h * 3; pp < h * 3 + 3; pp++) {
            int slot = pp * 512 + tid;
            const u16* gsrc;
            if (pp < 4) {
                int row = slot >> 3, p = slot & 7;
                int c = p ^ (row & 7);
                gsrc = g.A + (size_t)(m0 + row) * K + k0 + c * 8;
            } else {
                int s2 = slot - 2048;
                int row = s2 >> 3, p = s2 & 7;
                int c = p ^ (row & 7);
                gsrc = g.Bw + (size_t)(n0 + row) * K + k0 + c * 8;
            }
            gld16(gsrc, buf + slot * 8);
        }
    };

    f32x4 acc[4][4];
#pragma unroll
    for (int i = 0; i < 4; i++)
#pragma unroll
        for (int j = 0; j < 4; j++) acc[i][j] = (f32x4){0.f, 0.f, 0.f, 0.f};

    int nt = K >> 6;                 // 16 K-tiles of 64
    stage_half(0, &sbuf[0][0], 0);
    stage_half(0, &sbuf[0][0], 1);
    stage_half(64, &sbuf[1][0], 0);
    stage_half(64, &sbuf[1][0], 1);
    asm volatile("s_waitcnt vmcnt(6)" ::: "memory");   // tile 0 resident (tile 1's 6 may fly)
    asm volatile("s_barrier" ::: "memory");

    for (int t = 0; t < nt; ++t) {
        const u16* Ab = &sbuf[0][0] + (t % 3) * 24576;
        const u16* Bb = Ab + 16384;
        u16* nbuf = &sbuf[0][0] + ((t + 2) % 3) * 24576;
#pragma unroll
        for (int kk = 0; kk < 2; kk++) {
            bf16x8 af[4], bfr[4];
#pragma unroll
            for (int i = 0; i < 4; i++) {
                int row = wm * 64 + i * 16 + l16;
                af[i] = *(const bf16x8*)&Ab[row * 64 + (((kk << 2) | quad) ^ (row & 7)) * 8];
            }
#pragma unroll
            for (int j = 0; j < 4; j++) {
                int row = wn * 64 + j * 16 + l16;
                bfr[j] = *(const bf16x8*)&Bb[row * 64 + (((kk << 2) | quad) ^ (row & 7)) * 8];
            }
            if (t + 2 < nt) stage_half((t + 2) << 6, nbuf, kk);
            if (kk == 1) {
                if (t + 2 < nt) asm volatile("s_waitcnt vmcnt(6)" ::: "memory");
                else            asm volatile("s_waitcnt vmcnt(0)" ::: "memory");
            }
            asm volatile("s_barrier" ::: "memory");
            __builtin_amdgcn_s_setprio(1);
#pragma unroll
            for (int i = 0; i < 4; i++)
#pragma unroll
                for (int j = 0; j < 4; j++)
                    acc[i][j] = __builtin_amdgcn_mfma_f32_16x16x32_bf16(af[i], bfr[j], acc[i][j], 0, 0, 0);
            __builtin_amdgcn_s_setprio(0);
            asm volatile("s_barrier" ::: "memory");
        }
    }

    if (z < 2) {
        float qscale = (z == 0) ? 0.18033688011112042f : 1.0f;  // (1/8)*log2(e) for Q
#pragma unroll
        for (int j = 0; j < 2; j++) {
            int col1 = n0 + wn * 64 + j * 16 + l16;
            int dd1 = col1 & 63;                 // = j*16+l16, in [0,32)
            int h = col1 >> 6;
            float b1 = g.bias[col1], b2 = g.bias[col1 + 32];
#pragma unroll
            for (int i = 0; i < 4; i++)
#pragma unroll
                for (int r = 0; r < 4; r++) {
                    int row = m0 + wm * 64 + i * 16 + quad * 4 + r;
                    int b = row >> 11, s = row & (SEQ - 1);
                    float2 cs = g.rope[s * 32 + dd1];
                    float x1 = acc[i][j][r] + b1;
                    float x2 = acc[i][j + 2][r] + b2;
                    size_t base = ((size_t)(b * NH + h) * SEQ + s) << 6;
                    g.Cb[base + dd1]      = f2b((x1 * cs.x - x2 * cs.y) * qscale);
                    g.Cb[base + dd1 + 32] = f2b((x2 * cs.x + x1 * cs.y) * qscale);
                }
        }
    } else {
        // V -> [BH][D][S]: LDS transpose (overlays sbuf, XOR-swizzled) + coalesced stores.
        __syncthreads();                   // everyone done reading sbuf
        u16* tr = &sbuf[0][0] + wave * 4096;   // per-wave 64(d) x 64(s), c4-chunk swizzle
        int h = (n0 >> 6) + wn;
        int b = m0 >> 11;
        int s0 = (m0 & (SEQ - 1)) + wm * 64;
#pragma unroll
        for (int j = 0; j < 4; j++) {
            float bv = g.bias[n0 + wn * 64 + j * 16 + l16];
#pragma unroll
            for (int i = 0; i < 4; i++) {
                uint2 pk;
                pk.x = pack_bf16x2(acc[i][j][0] + bv, acc[i][j][1] + bv);
                pk.y = pack_bf16x2(acc[i][j][2] + bv, acc[i][j][3] + bv);
                int row = j * 16 + l16;                  // d-local
                int c4 = i * 4 + quad;                   // 4-u16 chunk index (s-local/4)
                *(uint2*)&tr[row * 64 + ((c4 ^ (row & 14)) << 2)] = pk;
            }
        }
        u16* dst = g.Cb + (((size_t)(b * NH + h) * HD) * SEQ) + s0;
#pragma unroll
        for (int ps = 0; ps < 8; ps++) {
            int d = ps * 8 + (lane >> 3);
            int c4 = (lane & 7) * 2;                     // even -> xor keeps pair contiguous
            uint4 v = *(const uint4*)&tr[d * 64 + ((c4 ^ (d & 14)) << 2)];
            *(uint4*)&dst[(size_t)d * SEQ + c4 * 4] = v;
        }
    }
}

// ---------------- output projection GEMM: 64x128 tiles, XCD-affinity swizzle ----------------
__global__ __launch_bounds__(256) void k_gemm_o(const u16* __restrict__ A,
                                                const u16* __restrict__ Bw,
                                                const float* __restrict__ bias,
                                                float* __restrict__ C) {
    __shared__ u16 sb[2][6144];          // A 64x32 (2048) + B 128x32 (4096)
    int tid = threadIdx.x;
    int w = tid >> 6, lane = tid & 63, quad = lane >> 4, l16 = lane & 15;
    int y = blockIdx.x & 63, x = blockIdx.x >> 6;   // id = x*64+y: same-y blocks share XCD
    int m0 = y * 64, n0 = x * 128;
    const int K = EMB;

    auto stage = [&](int k0, u16* buf) {
#pragma unroll
        for (int pp = 0; pp < 3; pp++) {
            int slot = pp * 256 + tid;
            if (slot < 256) {
                int row = slot >> 2, p = slot & 3;
                int c = p ^ (row & 3);
                gld16(A + (size_t)(m0 + row) * K + k0 + c * 8, buf + slot * 8);
            } else {
                int s2 = slot - 256;
                int row = s2 >> 2, p = s2 & 3;
                int c = p ^ (row & 3);
                gld16(Bw + (size_t)(n0 + row) * K + k0 + c * 8, buf + 2048 + s2 * 8);
            }
        }
    };

    f32x4 acc[4][2];
#pragma unroll
    for (int i = 0; i < 4; i++)
#pragma unroll
        for (int j = 0; j < 2; j++) acc[i][j] = (f32x4){0.f, 0.f, 0.f, 0.f};

    int nk = K >> 5;
    stage(0, sb[0]);
    for (int ks = 0; ks < nk; ks++) {
        __syncthreads();
        if (ks + 1 < nk) stage((ks + 1) << 5, sb[(ks + 1) & 1]);
        const u16* Ab = sb[ks & 1];
        const u16* Bb = Ab + 2048;
        bf16x8 af[4], bf[2];
#pragma unroll
        for (int i = 0; i < 4; i++) {
            int row = i * 16 + l16;
            af[i] = *(const bf16x8*)&Ab[row * 32 + (quad ^ (row & 3)) * 8];
        }
#pragma unroll
        for (int j = 0; j < 2; j++) {
            int row = w * 32 + j * 16 + l16;
            bf[j] = *(const bf16x8*)&Bb[row * 32 + (quad ^ (row & 3)) * 8];
        }
#pragma unroll
        for (int i = 0; i < 4; i++)
#pragma unroll
            for (int j = 0; j < 2; j++)
                acc[i][j] = __builtin_amdgcn_mfma_f32_16x16x32_bf16(af[i], bf[j], acc[i][j], 0, 0, 0);
    }

#pragma unroll
    for (int i = 0; i < 4; i++)
#pragma unroll
        for (int r = 0; r < 4; r++) {
            int row = m0 + i * 16 + quad * 4 + r;
#pragma unroll
            for (int j = 0; j < 2; j++) {
                int col = n0 + w * 32 + j * 16 + l16;
                C[(size_t)row * EMB + col] = acc[i][j][r] + bias[col];
            }
        }
}

// ---------------- flash attention, fixed-max softmax, t-split wave pairs ----------------
// Q pre-scaled by (1/8)*log2(e): MFMA output is in exp2 domain; p = exp2(s'-64),
// no online rescale -> partial (O,l) over disjoint t-ranges merge by PLAIN ADDITION.
// 512 threads = 4 q-pairs x 2 t-parities: wave w and w+4 own the same 32 q-rows;
// w computes even 64-t tiles, w+4 odd tiles. One barrier per 128 t.
// BALANCED LPT pairing: 2 blocks/CU, round-robin dispatch gives CU c ids
// {c, c+256}. qt = 15-(id>>5) for id<256 (long tiles), (id>>5)-8 for id>=256
// (short tiles) -> every CU's pair sums to exactly 17 tile-rounds (the old
// all-descending map paired 24 on CU 0 vs 10 on CU 224: ~1.4x critical path).
// id%32=bh for K/V L2 affinity per XCD.
// __launch_bounds__(512, 2): 2 blocks/CU (80 KB LDS) -> VGPR cap 128.
__global__ __launch_bounds__(512, 2) void k_attn(const u16* __restrict__ Q,
                                                 const u16* __restrict__ K,
                                                 const u16* __restrict__ Vt,
                                                 u16* __restrict__ O) {
    __shared__ u16 kv[4][8192];      // bufs 0,1: even-tile K|V double buffer; 2,3: odd-tile
    __shared__ u16 Pl[8][1024];      // per-wave P staging (one group at a time)
    int tid = threadIdx.x;
    int w = tid >> 6, lane = tid & 63, quad = lane >> 4, l16 = lane & 15;
    int pair = w & 3, par = w >> 2;
    int bh = blockIdx.x & 31;
    int qt = (blockIdx.x < 256) ? 15 - (blockIdx.x >> 5) : (blockIdx.x >> 5) - 8;
    int q0w = qt * 128 + pair * 32;

    const u16* Qb = Q + (size_t)bh * SEQ * HD;
    const u16* Kb = K + (size_t)bh * SEQ * HD;
    const u16* Vb = Vt + (size_t)bh * HD * SEQ;
    u16* pl = Pl[w];

    auto stage = [&](int t0, u16* buf) {
#pragma unroll
        for (int pp = 0; pp < 2; pp++) {
            int slot = pp * 512 + tid;
            int r = (slot >> 3) & 63;
            int p = slot & 7;
            int c = p ^ (r & 7);
            const u16* gsrc = (pp < 1) ? Kb + (size_t)(t0 + r) * HD + c * 8
                                       : Vb + (size_t)r * SEQ + t0 + c * 8;
            gld16(gsrc, buf + slot * 8);
        }
    };

    bf16x8 bq[2][2];
#pragma unroll
    for (int g = 0; g < 2; g++) {
        size_t base = (size_t)(q0w + g * 16 + l16) * HD + quad * 8;
        bq[g][0] = *(const bf16x8*)&Qb[base];
        bq[g][1] = *(const bf16x8*)&Qb[base + 32];
    }

    f32x4 o2[2][4];
#pragma unroll
    for (int g = 0; g < 2; g++)
#pragma unroll
        for (int jd = 0; jd < 4; jd++) o2[g][jd] = (f32x4){0.f, 0.f, 0.f, 0.f};
    float l_p[2] = {0.f, 0.f};

    int nsup = qt + 1;               // each super-iter covers tiles 2k (even) and 2k+1 (odd)
    stage(0, kv[0]);
    stage(64, kv[2]);
    for (int k = 0; k < nsup; ++k) {
        __syncthreads();
        if (k + 1 < nsup) {
            stage((k + 1) * 128,      kv[(k + 1) & 1]);
            stage((k + 1) * 128 + 64, kv[2 + ((k + 1) & 1)]);
        }
        int t0 = k * 128 + par * 64;
        if (t0 > q0w + 31) continue;     // wave fully masked (uniform): skip reads+compute

        const u16* Kl = kv[par * 2 + (k & 1)];
        const u16* Vl = Kl + 4096;

        bf16x8 kf[4][2], vf[4][2];
#pragma unroll
        for (int mt = 0; mt < 4; mt++) {
            int row = mt * 16 + l16;
            kf[mt][0] = *(const bf16x8*)&Kl[row * 64 + (quad ^ (row & 7)) * 8];
            kf[mt][1] = *(const bf16x8*)&Kl[row * 64 + ((quad + 4) ^ (row & 7)) * 8];
            vf[mt][0] = *(const bf16x8*)&Vl[row * 64 + (quad ^ (row & 7)) * 8];
            vf[mt][1] = *(const bf16x8*)&Vl[row * 64 + ((quad + 4) ^ (row & 7)) * 8];
        }

#pragma unroll
        for (int g = 0; g < 2; g++) {
            int qmin = q0w + g * 16;
            if (t0 > qmin + 15) continue;    // fully masked for this group (wave-uniform)

            f32x4 sc[4];
#pragma unroll
            for (int mt = 0; mt < 4; mt++) {
                sc[mt] = (f32x4){0.f, 0.f, 0.f, 0.f};
                sc[mt] = __builtin_amdgcn_mfma_f32_16x16x32_bf16(kf[mt][0], bq[g][0], sc[mt], 0, 0, 0);
                sc[mt] = __builtin_amdgcn_mfma_f32_16x16x32_bf16(kf[mt][1], bq[g][1], sc[mt], 0, 0, 0);
            }

            if (t0 + 63 > qmin) {
                int q = qmin + l16;
#pragma unroll
                for (int mt = 0; mt < 4; mt++)
#pragma unroll
                    for (int r = 0; r < 4; r++) {
                        int t = t0 + mt * 16 + quad * 4 + r;
                        if (t > q) sc[mt][r] = -INFINITY;
                    }
            }

            float rs = 0.f;
#pragma unroll
            for (int mt = 0; mt < 4; mt++)
#pragma unroll
                for (int r = 0; r < 4; r++) {
                    float p = __builtin_amdgcn_exp2f(sc[mt][r] - 64.f);
                    sc[mt][r] = p;
                    rs += p;
                }
            l_p[g] += rs;

#pragma unroll
            for (int mt = 0; mt < 4; mt++) {
                uint2 pk;
                pk.x = pack_bf16x2(sc[mt][0], sc[mt][1]);
                pk.y = pack_bf16x2(sc[mt][2], sc[mt][3]);
                int chunk = 2 * mt + (quad >> 1);
                *(uint2*)&pl[l16 * 64 + (chunk ^ (l16 & 7)) * 8 + (quad & 1) * 4] = pk;
            }

            bf16x8 pb0 = *(const bf16x8*)&pl[l16 * 64 + (quad ^ (l16 & 7)) * 8];
            bf16x8 pb1 = *(const bf16x8*)&pl[l16 * 64 + ((quad + 4) ^ (l16 & 7)) * 8];

#pragma unroll
            for (int jd = 0; jd < 4; jd++) {
                o2[g][jd] = __builtin_amdgcn_mfma_f32_16x16x32_bf16(vf[jd][0], pb0, o2[g][jd], 0, 0, 0);
                o2[g][jd] = __builtin_amdgcn_mfma_f32_16x16x32_bf16(vf[jd][1], pb1, o2[g][jd], 0, 0, 0);
            }
        }
    }

    // ---- merge odd-parity partials into even-parity waves (plain add: fixed max) ----
    __syncthreads();                      // all compute done; kv[] free for reuse
    float* mp = (float*)&kv[0][0] + pair * 2176;
    if (par) {
#pragma unroll
        for (int g = 0; g < 2; g++) {
#pragma unroll
            for (int jd = 0; jd < 4; jd++)
                *(f32x4*)&mp[(g * 4 + jd) * 256 + lane * 4] = o2[g][jd];
            mp[2048 + g * 64 + lane] = l_p[g];
        }
    }
    __syncthreads();
    if (par) return;                      // no further barriers below
#pragma unroll
    for (int g = 0; g < 2; g++) {
#pragma unroll
        for (int jd = 0; jd < 4; jd++)
            o2[g][jd] += *(const f32x4*)&mp[(g * 4 + jd) * 256 + lane * 4];
        l_p[g] += mp[2048 + g * 64 + lane];
    }

    // epilogue staging in kv[] beyond the merge region (merge: <34816B; ep: 36864B+)
    u16* ep = ((u16*)&kv[0][0]) + 18432 + pair * 1216;
    int b = bh >> 4, h = bh & (NH - 1);
#pragma unroll
    for (int g = 0; g < 2; g++) {
        float l = l_p[g];
        l += __shfl_xor(l, 16, 64);
        l += __shfl_xor(l, 32, 64);
        float inv = 1.f / l;
#pragma unroll
        for (int jd = 0; jd < 4; jd++) {
            uint2 pk;
            pk.x = pack_bf16x2(o2[g][jd][0] * inv, o2[g][jd][1] * inv);
            pk.y = pack_bf16x2(o2[g][jd][2] * inv, o2[g][jd][3] * inv);
            *(uint2*)&ep[l16 * 72 + jd * 16 + quad * 4] = pk;
        }
        int row = lane >> 2, dc = (lane & 3) * 16;
        uint4 d0 = *(const uint4*)&ep[row * 72 + dc];
        uint4 d1 = *(const uint4*)&ep[row * 72 + dc + 8];
        int q = q0w + g * 16 + row;
        size_t addr = (size_t)(b * SEQ + q) * EMB + h * HD + dc;
        *(uint4*)&O[addr] = d0;
        *(uint4*)&O[addr + 8] = d1;
    }
}

extern "C" void kernel_launch(void* const* d_in, const int* in_sizes, int n_in,
                              void* d_out, int out_size, void* d_ws, size_t ws_size,
                              hipStream_t stream) {
    const float* query = (const float*)d_in[0];
    const float* key_  = (const float*)d_in[1];
    const float* value = (const float*)d_in[2];
    const float* Wq = (const float*)d_in[3];
    const float* bq = (const float*)d_in[4];
    const float* Wk = (const float*)d_in[5];
    const float* bk = (const float*)d_in[6];
    const float* Wv = (const float*)d_in[7];
    const float* bv = (const float*)d_in[8];
    const float* Wo = (const float*)d_in[9];
    const float* bo = (const float*)d_in[10];
    float* out = (float*)d_out;

    char* ws = (char*)d_ws;
    const size_t MB = 1u << 20;
    u16* xq  = (u16*)(ws + 0 * MB);
    u16* xk  = (u16*)(ws + 8 * MB);    // reused as Ab (attn out)
    u16* xv  = (u16*)(ws + 16 * MB);
    u16* wqb = (u16*)(ws + 24 * MB);
    u16* wkb = (u16*)(ws + 26 * MB);
    u16* wvb = (u16*)(ws + 28 * MB);
    u16* wob = (u16*)(ws + 30 * MB);
    u16* Qp  = (u16*)(ws + 32 * MB);   // Q with RoPE+scale, [B,H,S,D]
    u16* Kp  = (u16*)(ws + 40 * MB);   // K with RoPE, [B,H,S,D]
    u16* Vt  = (u16*)(ws + 48 * MB);   // V transposed, [B,H,D,S]
    float2* tbl = (float2*)(ws + 56 * MB);  // RoPE table [2048][32] float2
    u16* Ab  = xk;

    F2BArgs fa;
    fa.s[0] = query; fa.s[1] = key_; fa.s[2] = value;
    fa.s[3] = Wq; fa.s[4] = Wk; fa.s[5] = Wv; fa.s[6] = Wo;
    fa.d[0] = xq; fa.d[1] = xk; fa.d[2] = xv;
    fa.d[3] = wqb; fa.d[4] = wkb; fa.d[5] = wvb; fa.d[6] = wob;
    fa.tbl = tbl;
    k_f2b<<<8256, 256, 0, stream>>>(fa);

    GemmArgs gq = { xq, wqb, bq, Qp, tbl };
    GemmArgs gk = { xk, wkb, bk, Kp, tbl };
    GemmArgs gv = { xv, wvb, bv, Vt, tbl };
    k_gemm_qkv<<<384, 512, 0, stream>>>(gq, gk, gv);

    k_attn<<<512, 512, 0, stream>>>(Qp, Kp, Vt, Ab);

    k_gemm_o<<<512, 256, 0, stream>>>(Ab, wob, bo, out);
}

// Round 8
// 201.313 us; speedup vs baseline: 1.1178x; 1.1178x over previous
//
#include <hip/hip_runtime.h>
#include <math.h>

typedef unsigned short u16;
typedef __attribute__((ext_vector_type(4))) float f32x4;
typedef __attribute__((ext_vector_type(8))) short bf16x8;

#define SEQ   2048
#define EMB   1024
#define NH    16
#define HD    64
#define MROWS 4096   // B*S

__device__ __forceinline__ u16 f2b(float f) {
    unsigned u = __float_as_uint(f);
    u += 0x7fff + ((u >> 16) & 1);   // RNE
    return (u16)(u >> 16);
}
__device__ __forceinline__ unsigned pack_bf16x2(float a, float b) {
    unsigned ua = __float_as_uint(a) + 0x8000u;
    unsigned ub = __float_as_uint(b) + 0x8000u;
    return __builtin_amdgcn_perm(ub, ua, 0x07060302u);
}
__device__ __forceinline__ void gld16(const u16* g, const u16* l) {
    __builtin_amdgcn_global_load_lds((const __attribute__((address_space(1))) void*)g,
                                     (__attribute__((address_space(3))) void*)l, 16, 0, 0);
}

// ---------------- fp32 -> bf16 convert (single merged dispatch) ----------------
struct F2BArgs { const float* s[7]; u16* d[7]; };

__global__ void k_f2b(F2BArgs a) {
    int id = blockIdx.x;
    const float* src; u16* dst; int base;
    if (id < 6144) {              // 3 activation tensors, 2048 blocks each
        int z = id >> 11;
        src = a.s[z]; dst = a.d[z];
        base = (id & 2047) << 8;
    } else {                      // 4 weight tensors, 512 blocks each
        int r = id - 6144;
        int z = 3 + (r >> 9);
        src = a.s[z]; dst = a.d[z];
        base = (r & 511) << 8;
    }
    int i = base + threadIdx.x;   // index in units of 8 elements
    const float4* s4 = (const float4*)src;
    float4 x = s4[i * 2], y = s4[i * 2 + 1];
    union { u16 u[8]; uint4 v; } o;
    o.u[0] = f2b(x.x); o.u[1] = f2b(x.y); o.u[2] = f2b(x.z); o.u[3] = f2b(x.w);
    o.u[4] = f2b(y.x); o.u[5] = f2b(y.y); o.u[6] = f2b(y.z); o.u[7] = f2b(y.w);
    ((uint4*)dst)[i] = o.v;
}

// ---------------- QKV GEMM: C[M,N] = A[M,K] @ B[N,K]^T + bias ----------------
// R3 skeleton (best measured: 42 us): BM=256 x BN=128, BK=64, 8 waves, 3
// K-tile LDS buffers (144 KB), conflict-free p^(row&7) swizzle, counted vmcnt
// (6 loads/tile, wait own stage(t) at tile end, never drain mid-loop).
// NEW: 4 fine phases per K-tile (kk x i-half), each
//   { 2 af ds_read (+4 bfr at kk-start) || 2-load stage chunk of tile t+2
//     [last phase: vmcnt(6|0)] ; barrier ; setprio(1) ; 8 MFMA ; setprio(0) ; barrier }
// Phase p+1's ds_reads issue while phase p's MFMAs drain (s_barrier doesn't
// wait MFMA completion; af regs disjoint across phases) -> LDS pipe works
// under MFMA execution. Diagnosis: kernel is LDS-pipe-bound (~1400 cyc LDS vs
// ~320 cyc MFMA per tile -> 23% MfmaUtil ceiling = measured), so the only
// lever is overlapping the two pipes (m248v2: 8ph/2ph = 1.10x).
// Epilogue: __sincosf RoPE (R7's table gather cost +10us -- reverted).
struct GemmArgs {
    const u16* A; const u16* Bw; const float* bias; u16* Cb;
};

__global__ __launch_bounds__(512, 2) void k_gemm_qkv(GemmArgs g0, GemmArgs g1, GemmArgs g2) {
    __shared__ u16 sbuf[3][24576];   // 3 K-tile buffers: A 256x64 (16K u16) + B 128x64 (8K u16)

    int id = blockIdx.x;
    int x = id / 48;
    int rem = id % 48;
    int z = rem >> 4;
    int y = rem & 15;
    GemmArgs g = (z == 0) ? g0 : (z == 1 ? g1 : g2);

    int tid = threadIdx.x;
    int wave = tid >> 6, lane = tid & 63, quad = lane >> 4, l16 = lane & 15;
    int wm = wave >> 1, wn = wave & 1;
    int m0 = y * 256, n0 = x * 128;
    const int K = EMB;

    // chunk c in {0,1,2}: pp in {2c, 2c+1} of the 6 512-thread load chunks
    auto stage_pair = [&](int k0, u16* buf, int c) {
#pragma unroll
        for (int pp = c * 2; pp < c * 2 + 2; pp++) {
            int slot = pp * 512 + tid;
            const u16* gsrc;
            if (pp < 4) {
                int row = slot >> 3, p = slot & 7;
                int cc = p ^ (row & 7);
                gsrc = g.A + (size_t)(m0 + row) * K + k0 + cc * 8;
            } else {
                int s2 = slot - 2048;
                int row = s2 >> 3, p = s2 & 7;
                int cc = p ^ (row & 7);
                gsrc = g.Bw + (size_t)(n0 + row) * K + k0 + cc * 8;
            }
            gld16(gsrc, buf + slot * 8);
        }
    };

    f32x4 acc[4][4];
#pragma unroll
    for (int i = 0; i < 4; i++)
#pragma unroll
        for (int j = 0; j < 4; j++) acc[i][j] = (f32x4){0.f, 0.f, 0.f, 0.f};

    int nt = K >> 6;                 // 16 K-tiles of 64
    stage_pair(0, &sbuf[0][0], 0);
    stage_pair(0, &sbuf[0][0], 1);
    stage_pair(0, &sbuf[0][0], 2);
    stage_pair(64, &sbuf[1][0], 0);
    stage_pair(64, &sbuf[1][0], 1);
    stage_pair(64, &sbuf[1][0], 2);
    asm volatile("s_waitcnt vmcnt(6)" ::: "memory");   // tile 0 resident (tile 1's 6 may fly)
    asm volatile("s_barrier" ::: "memory");

    for (int t = 0; t < nt; ++t) {
        const u16* Ab = &sbuf[0][0] + (t % 3) * 24576;
        const u16* Bb = Ab + 16384;
        u16* nbuf = &sbuf[0][0] + ((t + 2) % 3) * 24576;
        bf16x8 af[4], bfr[4];
#pragma unroll
        for (int p = 0; p < 4; p++) {
            int kk = p >> 1, ih = p & 1;
            // ds_reads for THIS phase's MFMAs (af disjoint across phases ->
            // they issue while the previous phase's MFMAs drain)
#pragma unroll
            for (int i2 = 0; i2 < 2; i2++) {
                int i = ih * 2 + i2;
                int row = wm * 64 + i * 16 + l16;
                af[i] = *(const bf16x8*)&Ab[row * 64 + (((kk << 2) | quad) ^ (row & 7)) * 8];
            }
            if (ih == 0) {
#pragma unroll
                for (int j = 0; j < 4; j++) {
                    int row = wn * 64 + j * 16 + l16;
                    bfr[j] = *(const bf16x8*)&Bb[row * 64 + (((kk << 2) | quad) ^ (row & 7)) * 8];
                }
            }
            if (p < 3) {
                if (t + 2 < nt) stage_pair((t + 2) << 6, nbuf, p);
            } else {
                if (t + 2 < nt) asm volatile("s_waitcnt vmcnt(6)" ::: "memory");
                else            asm volatile("s_waitcnt vmcnt(0)" ::: "memory");
            }
            asm volatile("s_barrier" ::: "memory");
            __builtin_amdgcn_s_setprio(1);
#pragma unroll
            for (int i2 = 0; i2 < 2; i2++)
#pragma unroll
                for (int j = 0; j < 4; j++) {
                    int i = ih * 2 + i2;
                    acc[i][j] = __builtin_amdgcn_mfma_f32_16x16x32_bf16(af[i], bfr[j], acc[i][j], 0, 0, 0);
                }
            __builtin_amdgcn_s_setprio(0);
            asm volatile("s_barrier" ::: "memory");
        }
    }

    if (z < 2) {
        float qscale = (z == 0) ? 0.18033688011112042f : 1.0f;  // (1/8)*log2(e) for Q
#pragma unroll
        for (int j = 0; j < 2; j++) {
            int col1 = n0 + wn * 64 + j * 16 + l16;
            int dd1 = col1 & 63;
            int h = col1 >> 6;
            float inv = __expf(-(float)dd1 * 0.28782313662425575f);  // ln(10000)/32
            float b1 = g.bias[col1], b2 = g.bias[col1 + 32];
#pragma unroll
            for (int i = 0; i < 4; i++)
#pragma unroll
                for (int r = 0; r < 4; r++) {
                    int row = m0 + wm * 64 + i * 16 + quad * 4 + r;
                    int b = row >> 11, s = row & (SEQ - 1);
                    float sn, cs;
                    __sincosf((float)s * inv, &sn, &cs);
                    float x1 = acc[i][j][r] + b1;
                    float x2 = acc[i][j + 2][r] + b2;
                    size_t base = ((size_t)(b * NH + h) * SEQ + s) << 6;
                    g.Cb[base + dd1]      = f2b((x1 * cs - x2 * sn) * qscale);
                    g.Cb[base + dd1 + 32] = f2b((x2 * cs + x1 * sn) * qscale);
                }
        }
    } else {
        // V -> [BH][D][S]: LDS transpose (overlays sbuf, XOR-swizzled) + coalesced stores.
        __syncthreads();                   // everyone done reading sbuf
        u16* tr = &sbuf[0][0] + wave * 4096;   // per-wave 64(d) x 64(s), c4-chunk swizzle
        int h = (n0 >> 6) + wn;
        int b = m0 >> 11;
        int s0 = (m0 & (SEQ - 1)) + wm * 64;
#pragma unroll
        for (int j = 0; j < 4; j++) {
            float bv = g.bias[n0 + wn * 64 + j * 16 + l16];
#pragma unroll
            for (int i = 0; i < 4; i++) {
                uint2 pk;
                pk.x = pack_bf16x2(acc[i][j][0] + bv, acc[i][j][1] + bv);
                pk.y = pack_bf16x2(acc[i][j][2] + bv, acc[i][j][3] + bv);
                int row = j * 16 + l16;                  // d-local
                int c4 = i * 4 + quad;                   // 4-u16 chunk index (s-local/4)
                *(uint2*)&tr[row * 64 + ((c4 ^ (row & 14)) << 2)] = pk;
            }
        }
        u16* dst = g.Cb + (((size_t)(b * NH + h) * HD) * SEQ) + s0;
#pragma unroll
        for (int ps = 0; ps < 8; ps++) {
            int d = ps * 8 + (lane >> 3);
            int c4 = (lane & 7) * 2;                     // even -> xor keeps pair contiguous
            uint4 v = *(const uint4*)&tr[d * 64 + ((c4 ^ (d & 14)) << 2)];
            *(uint4*)&dst[(size_t)d * SEQ + c4 * 4] = v;
        }
    }
}

// ---------------- output projection GEMM: 64x128 tiles, XCD-affinity swizzle ----------------
__global__ __launch_bounds__(256) void k_gemm_o(const u16* __restrict__ A,
                                                const u16* __restrict__ Bw,
                                                const float* __restrict__ bias,
                                                float* __restrict__ C) {
    __shared__ u16 sb[2][6144];          // A 64x32 (2048) + B 128x32 (4096)
    int tid = threadIdx.x;
    int w = tid >> 6, lane = tid & 63, quad = lane >> 4, l16 = lane & 15;
    int y = blockIdx.x & 63, x = blockIdx.x >> 6;   // id = x*64+y: same-y blocks share XCD
    int m0 = y * 64, n0 = x * 128;
    const int K = EMB;

    auto stage = [&](int k0, u16* buf) {
#pragma unroll
        for (int pp = 0; pp < 3; pp++) {
            int slot = pp * 256 + tid;
            if (slot < 256) {
                int row = slot >> 2, p = slot & 3;
                int c = p ^ (row & 3);
                gld16(A + (size_t)(m0 + row) * K + k0 + c * 8, buf + slot * 8);
            } else {
                int s2 = slot - 256;
                int row = s2 >> 2, p = s2 & 3;
                int c = p ^ (row & 3);
                gld16(Bw + (size_t)(n0 + row) * K + k0 + c * 8, buf + 2048 + s2 * 8);
            }
        }
    };

    f32x4 acc[4][2];
#pragma unroll
    for (int i = 0; i < 4; i++)
#pragma unroll
        for (int j = 0; j < 2; j++) acc[i][j] = (f32x4){0.f, 0.f, 0.f, 0.f};

    int nk = K >> 5;
    stage(0, sb[0]);
    for (int ks = 0; ks < nk; ks++) {
        __syncthreads();
        if (ks + 1 < nk) stage((ks + 1) << 5, sb[(ks + 1) & 1]);
        const u16* Ab = sb[ks & 1];
        const u16* Bb = Ab + 2048;
        bf16x8 af[4], bf[2];
#pragma unroll
        for (int i = 0; i < 4; i++) {
            int row = i * 16 + l16;
            af[i] = *(const bf16x8*)&Ab[row * 32 + (quad ^ (row & 3)) * 8];
        }
#pragma unroll
        for (int j = 0; j < 2; j++) {
            int row = w * 32 + j * 16 + l16;
            bf[j] = *(const bf16x8*)&Bb[row * 32 + (quad ^ (row & 3)) * 8];
        }
#pragma unroll
        for (int i = 0; i < 4; i++)
#pragma unroll
            for (int j = 0; j < 2; j++)
                acc[i][j] = __builtin_amdgcn_mfma_f32_16x16x32_bf16(af[i], bf[j], acc[i][j], 0, 0, 0);
    }

#pragma unroll
    for (int i = 0; i < 4; i++)
#pragma unroll
        for (int r = 0; r < 4; r++) {
            int row = m0 + i * 16 + quad * 4 + r;
#pragma unroll
            for (int j = 0; j < 2; j++) {
                int col = n0 + w * 32 + j * 16 + l16;
                C[(size_t)row * EMB + col] = acc[i][j][r] + bias[col];
            }
        }
}

// ---------------- flash attention, fixed-max softmax, t-split wave pairs ----------------
// Q pre-scaled by (1/8)*log2(e): MFMA output is in exp2 domain; p = exp2(s'-64),
// no online rescale -> partial (O,l) over disjoint t-ranges merge by PLAIN ADDITION.
// 512 threads = 4 q-pairs x 2 t-parities: wave w and w+4 own the same 32 q-rows;
// w computes even 64-t tiles, w+4 odd tiles. One barrier per 128 t. LPT order
// qt = 15-(id>>5): REVERTED to the proven map (R7's "balanced" pairing put the
// longest block with the shortest on the heaviest CU -> half-occupied critical
// path, ~+9us). id%32=bh for K/V L2 affinity per XCD.
// __launch_bounds__(512, 2): 2 blocks/CU (80 KB LDS) -> VGPR cap 128.
__global__ __launch_bounds__(512, 2) void k_attn(const u16* __restrict__ Q,
                                                 const u16* __restrict__ K,
                                                 const u16* __restrict__ Vt,
                                                 u16* __restrict__ O) {
    __shared__ u16 kv[4][8192];      // bufs 0,1: even-tile K|V double buffer; 2,3: odd-tile
    __shared__ u16 Pl[8][1024];      // per-wave P staging (one group at a time)
    int tid = threadIdx.x;
    int w = tid >> 6, lane = tid & 63, quad = lane >> 4, l16 = lane & 15;
    int pair = w & 3, par = w >> 2;
    int bh = blockIdx.x & 31;
    int qt = 15 - (blockIdx.x >> 5);     // long q-tiles first in dispatch order
    int q0w = qt * 128 + pair * 32;

    const u16* Qb = Q + (size_t)bh * SEQ * HD;
    const u16* Kb = K + (size_t)bh * SEQ * HD;
    const u16* Vb = Vt + (size_t)bh * HD * SEQ;
    u16* pl = Pl[w];

    auto stage = [&](int t0, u16* buf) {
#pragma unroll
        for (int pp = 0; pp < 2; pp++) {
            int slot = pp * 512 + tid;
            int r = (slot >> 3) & 63;
            int p = slot & 7;
            int c = p ^ (r & 7);
            const u16* gsrc = (pp < 1) ? Kb + (size_t)(t0 + r) * HD + c * 8
                                       : Vb + (size_t)r * SEQ + t0 + c * 8;
            gld16(gsrc, buf + slot * 8);
        }
    };

    bf16x8 bq[2][2];
#pragma unroll
    for (int g = 0; g < 2; g++) {
        size_t base = (size_t)(q0w + g * 16 + l16) * HD + quad * 8;
        bq[g][0] = *(const bf16x8*)&Qb[base];
        bq[g][1] = *(const bf16x8*)&Qb[base + 32];
    }

    f32x4 o2[2][4];
#pragma unroll
    for (int g = 0; g < 2; g++)
#pragma unroll
        for (int jd = 0; jd < 4; jd++) o2[g][jd] = (f32x4){0.f, 0.f, 0.f, 0.f};
    float l_p[2] = {0.f, 0.f};

    int nsup = qt + 1;               // each super-iter covers tiles 2k (even) and 2k+1 (odd)
    stage(0, kv[0]);
    stage(64, kv[2]);
    for (int k = 0; k < nsup; ++k) {
        __syncthreads();
        if (k + 1 < nsup) {
            stage((k + 1) * 128,      kv[(k + 1) & 1]);
            stage((k + 1) * 128 + 64, kv[2 + ((k + 1) & 1)]);
        }
        int t0 = k * 128 + par * 64;
        if (t0 > q0w + 31) continue;     // wave fully masked (uniform): skip reads+compute

        const u16* Kl = kv[par * 2 + (k & 1)];
        const u16* Vl = Kl + 4096;

        bf16x8 kf[4][2], vf[4][2];
#pragma unroll
        for (int mt = 0; mt < 4; mt++) {
            int row = mt * 16 + l16;
            kf[mt][0] = *(const bf16x8*)&Kl[row * 64 + (quad ^ (row & 7)) * 8];
            kf[mt][1] = *(const bf16x8*)&Kl[row * 64 + ((quad + 4) ^ (row & 7)) * 8];
            vf[mt][0] = *(const bf16x8*)&Vl[row * 64 + (quad ^ (row & 7)) * 8];
            vf[mt][1] = *(const bf16x8*)&Vl[row * 64 + ((quad + 4) ^ (row & 7)) * 8];
        }

#pragma unroll
        for (int g = 0; g < 2; g++) {
            int qmin = q0w + g * 16;
            if (t0 > qmin + 15) continue;    // fully masked for this group (wave-uniform)

            f32x4 sc[4];
#pragma unroll
            for (int mt = 0; mt < 4; mt++) {
                sc[mt] = (f32x4){0.f, 0.f, 0.f, 0.f};
                sc[mt] = __builtin_amdgcn_mfma_f32_16x16x32_bf16(kf[mt][0], bq[g][0], sc[mt], 0, 0, 0);
                sc[mt] = __builtin_amdgcn_mfma_f32_16x16x32_bf16(kf[mt][1], bq[g][1], sc[mt], 0, 0, 0);
            }

            if (t0 + 63 > qmin) {
                int q = qmin + l16;
#pragma unroll
                for (int mt = 0; mt < 4; mt++)
#pragma unroll
                    for (int r = 0; r < 4; r++) {
                        int t = t0 + mt * 16 + quad * 4 + r;
                        if (t > q) sc[mt][r] = -INFINITY;
                    }
            }

            float rs = 0.f;
#pragma unroll
            for (int mt = 0; mt < 4; mt++)
#pragma unroll
                for (int r = 0; r < 4; r++) {
                    float p = __builtin_amdgcn_exp2f(sc[mt][r] - 64.f);
                    sc[mt][r] = p;
                    rs += p;
                }
            l_p[g] += rs;

#pragma unroll
            for (int mt = 0; mt < 4; mt++) {
                uint2 pk;
                pk.x = pack_bf16x2(sc[mt][0], sc[mt][1]);
                pk.y = pack_bf16x2(sc[mt][2], sc[mt][3]);
                int chunk = 2 * mt + (quad >> 1);
                *(uint2*)&pl[l16 * 64 + (chunk ^ (l16 & 7)) * 8 + (quad & 1) * 4] = pk;
            }

            bf16x8 pb0 = *(const bf16x8*)&pl[l16 * 64 + (quad ^ (l16 & 7)) * 8];
            bf16x8 pb1 = *(const bf16x8*)&pl[l16 * 64 + ((quad + 4) ^ (l16 & 7)) * 8];

#pragma unroll
            for (int jd = 0; jd < 4; jd++) {
                o2[g][jd] = __builtin_amdgcn_mfma_f32_16x16x32_bf16(vf[jd][0], pb0, o2[g][jd], 0, 0, 0);
                o2[g][jd] = __builtin_amdgcn_mfma_f32_16x16x32_bf16(vf[jd][1], pb1, o2[g][jd], 0, 0, 0);
            }
        }
    }

    // ---- merge odd-parity partials into even-parity waves (plain add: fixed max) ----
    __syncthreads();                      // all compute done; kv[] free for reuse
    float* mp = (float*)&kv[0][0] + pair * 2176;
    if (par) {
#pragma unroll
        for (int g = 0; g < 2; g++) {
#pragma unroll
            for (int jd = 0; jd < 4; jd++)
                *(f32x4*)&mp[(g * 4 + jd) * 256 + lane * 4] = o2[g][jd];
            mp[2048 + g * 64 + lane] = l_p[g];
        }
    }
    __syncthreads();
    if (par) return;                      // no further barriers below
#pragma unroll
    for (int g = 0; g < 2; g++) {
#pragma unroll
        for (int jd = 0; jd < 4; jd++)
            o2[g][jd] += *(const f32x4*)&mp[(g * 4 + jd) * 256 + lane * 4];
        l_p[g] += mp[2048 + g * 64 + lane];
    }

    // epilogue staging in kv[] beyond the merge region (merge: <34816B; ep: 36864B+)
    u16* ep = ((u16*)&kv[0][0]) + 18432 + pair * 1216;
    int b = bh >> 4, h = bh & (NH - 1);
#pragma unroll
    for (int g = 0; g < 2; g++) {
        float l = l_p[g];
        l += __shfl_xor(l, 16, 64);
        l += __shfl_xor(l, 32, 64);
        float inv = 1.f / l;
#pragma unroll
        for (int jd = 0; jd < 4; jd++) {
            uint2 pk;
            pk.x = pack_bf16x2(o2[g][jd][0] * inv, o2[g][jd][1] * inv);
            pk.y = pack_bf16x2(o2[g][jd][2] * inv, o2[g][jd][3] * inv);
            *(uint2*)&ep[l16 * 72 + jd * 16 + quad * 4] = pk;
        }
        int row = lane >> 2, dc = (lane & 3) * 16;
        uint4 d0 = *(const uint4*)&ep[row * 72 + dc];
        uint4 d1 = *(const uint4*)&ep[row * 72 + dc + 8];
        int q = q0w + g * 16 + row;
        size_t addr = (size_t)(b * SEQ + q) * EMB + h * HD + dc;
        *(uint4*)&O[addr] = d0;
        *(uint4*)&O[addr + 8] = d1;
    }
}

extern "C" void kernel_launch(void* const* d_in, const int* in_sizes, int n_in,
                              void* d_out, int out_size, void* d_ws, size_t ws_size,
                              hipStream_t stream) {
    const float* query = (const float*)d_in[0];
    const float* key_  = (const float*)d_in[1];
    const float* value = (const float*)d_in[2];
    const float* Wq = (const float*)d_in[3];
    const float* bq = (const float*)d_in[4];
    const float* Wk = (const float*)d_in[5];
    const float* bk = (const float*)d_in[6];
    const float* Wv = (const float*)d_in[7];
    const float* bv = (const float*)d_in[8];
    const float* Wo = (const float*)d_in[9];
    const float* bo = (const float*)d_in[10];
    float* out = (float*)d_out;

    char* ws = (char*)d_ws;
    const size_t MB = 1u << 20;
    u16* xq  = (u16*)(ws + 0 * MB);
    u16* xk  = (u16*)(ws + 8 * MB);    // reused as Ab (attn out)
    u16* xv  = (u16*)(ws + 16 * MB);
    u16* wqb = (u16*)(ws + 24 * MB);
    u16* wkb = (u16*)(ws + 26 * MB);
    u16* wvb = (u16*)(ws + 28 * MB);
    u16* wob = (u16*)(ws + 30 * MB);
    u16* Qp  = (u16*)(ws + 32 * MB);   // Q with RoPE+scale, [B,H,S,D]
    u16* Kp  = (u16*)(ws + 40 * MB);   // K with RoPE, [B,H,S,D]
    u16* Vt  = (u16*)(ws + 48 * MB);   // V transposed, [B,H,D,S]
    u16* Ab  = xk;

    F2BArgs fa;
    fa.s[0] = query; fa.s[1] = key_; fa.s[2] = value;
    fa.s[3] = Wq; fa.s[4] = Wk; fa.s[5] = Wv; fa.s[6] = Wo;
    fa.d[0] = xq; fa.d[1] = xk; fa.d[2] = xv;
    fa.d[3] = wqb; fa.d[4] = wkb; fa.d[5] = wvb; fa.d[6] = wob;
    k_f2b<<<8192, 256, 0, stream>>>(fa);

    GemmArgs gq = { xq, wqb, bq, Qp };
    GemmArgs gk = { xk, wkb, bk, Kp };
    GemmArgs gv = { xv, wvb, bv, Vt };
    k_gemm_qkv<<<384, 512, 0, stream>>>(gq, gk, gv);

    k_attn<<<512, 512, 0, stream>>>(Qp, Kp, Vt, Ab);

    k_gemm_o<<<512, 256, 0, stream>>>(Ab, wob, bo, out);
}